// Round 9
// baseline (389.773 us; speedup 1.0000x reference)
//
#include <hip/hip_runtime.h>

#define D 256
#define B 128
#define S 64
#define L 32
#define K 32
#define NW 4      // waves per recurrence block (256 threads), 64 cols/wave
#define NSUB 4    // 16-col sub-tiles per wave
#define HSTR 260  // u16 stride (proven 0-conflict R7/R8)

typedef _Float16 f16x8 __attribute__((ext_vector_type(8)));  // 8 f16 in 4 VGPRs
typedef float f32x4 __attribute__((ext_vector_type(4)));
typedef unsigned short u16;

__device__ __forceinline__ u16 h_bits(_Float16 h) {
    union { _Float16 h; u16 u; } x; x.h = h; return x.u;
}

// ---------------------------------------------------------------------------
// sent_mask extraction, robust to bool shipped as 1-byte or int32.
// ---------------------------------------------------------------------------
__global__ void mask_kernel(const void* mraw, int* mask_out) {
    __shared__ int flag;
    const int tid = threadIdx.x;
    if (tid == 0) flag = 0;
    __syncthreads();
    const unsigned int* w32 = (const unsigned int*)mraw;
    int loc = 0;
    for (int i = tid; i < 1024; i += 256)
        if (w32[i] > 1u) loc = 1;
    if (loc) flag = 1;   // benign race
    __syncthreads();
    const bool is_bytes = (flag != 0);
    const unsigned char* b8 = (const unsigned char*)mraw;
    const int* i32 = (const int*)mraw;
    for (int i = tid; i < B * S; i += 256)
        mask_out[i] = is_bytes ? (int)b8[(size_t)i * L] : i32[(size_t)i * L];
}

// ---------------------------------------------------------------------------
// enc_sents[b,s,:] = sum_l E[prgrph[b,s,l], :]  (R5 version: 2048 blocks ->
// good latency hiding for the gather; fused 256-block version was slower)
// ---------------------------------------------------------------------------
__global__ __launch_bounds__(256) void embed_kernel(
    const int* __restrict__ prgrph, const float* __restrict__ E,
    float* __restrict__ enc) {
    const int t = threadIdx.x;
    const int g = t >> 6;                // sentence within block
    const int bs = blockIdx.x * 4 + g;
    const int c4 = t & 63;               // float4 column group
    __shared__ int sidx[4][L];
    if (t < 4 * L) sidx[t >> 5][t & 31] = prgrph[(size_t)blockIdx.x * 4 * L + t];
    __syncthreads();
    const float4* E4 = (const float4*)E;
    float4 a = make_float4(0.f, 0.f, 0.f, 0.f);
    #pragma unroll
    for (int l = 0; l < L; ++l) {
        const float4 v = E4[(size_t)sidx[g][l] * (D / 4) + c4];
        a.x += v.x; a.y += v.y; a.z += v.z; a.w += v.w;
    }
    *(float4*)&enc[(size_t)bs * D + c4 * 4] = a;
}

// ---------------------------------------------------------------------------
// O[r,:] = A[r,:] @ Bm, 32 rows/block (enc@W and keys@V).
// ---------------------------------------------------------------------------
__global__ __launch_bounds__(256) void gemm_f32_kernel(
    const float* __restrict__ A, const float* __restrict__ Bm,
    float* __restrict__ O) {
    const int row0 = blockIdx.x * 32;
    const int t = threadIdx.x, wave = t >> 6, lane = t & 63;
    __shared__ float a_s[32 * D];
    const float4* Ag = (const float4*)(A + (size_t)row0 * D);
    float4* As4 = (float4*)a_s;
    for (int i = t; i < 32 * D / 4; i += 256) As4[i] = Ag[i];
    __syncthreads();
    const int r0 = wave * 8, c0 = lane * 4;
    float4 acc[8];
    #pragma unroll
    for (int i = 0; i < 8; ++i) acc[i] = make_float4(0.f, 0.f, 0.f, 0.f);
    for (int d = 0; d < D; d += 4) {
        float4 av[8];
        #pragma unroll
        for (int i = 0; i < 8; ++i) av[i] = *(const float4*)&a_s[(r0 + i) * D + d];
        #pragma unroll
        for (int j = 0; j < 4; ++j) {
            const float4 w = *(const float4*)(Bm + (size_t)(d + j) * D + c0);
            #pragma unroll
            for (int i = 0; i < 8; ++i) {
                const float a = (j == 0) ? av[i].x : (j == 1) ? av[i].y
                              : (j == 2) ? av[i].z : av[i].w;
                acc[i].x += a * w.x; acc[i].y += a * w.y;
                acc[i].z += a * w.z; acc[i].w += a * w.w;
            }
        }
    }
    #pragma unroll
    for (int i = 0; i < 8; ++i)
        *(float4*)&O[(size_t)(row0 + r0 + i) * D + c0] = acc[i];
}

// ---------------------------------------------------------------------------
// ek[b,s,k] = enc[b,s,:] . keys[b,k,:]
// ---------------------------------------------------------------------------
__global__ __launch_bounds__(256) void ek_kernel(
    const float* __restrict__ enc, const float* __restrict__ keys,
    float* __restrict__ ek) {
    const int b = blockIdx.x, t = threadIdx.x;
    __shared__ float ks[K][D + 4];
    const float4* kg = (const float4*)(keys + (size_t)b * K * D);
    for (int i = t; i < K * D / 4; i += 256)
        *(float4*)&ks[i >> 6][(i & 63) * 4] = kg[i];
    __syncthreads();
    const int s = t >> 2, kq = t & 3;          // k = kq + 4j
    const float4* e4 = (const float4*)(enc + (size_t)(b * S + s) * D);
    float acc[8];
    #pragma unroll
    for (int j = 0; j < 8; ++j) acc[j] = 0.f;
    for (int d4 = 0; d4 < D / 4; ++d4) {
        const float4 e = e4[d4];
        #pragma unroll
        for (int j = 0; j < 8; ++j) {
            const float4 kv = *(const float4*)&ks[kq + 4 * j][d4 * 4];
            acc[j] += e.x * kv.x + e.y * kv.y + e.z * kv.z + e.w * kv.w;
        }
    }
    #pragma unroll
    for (int j = 0; j < 8; ++j)
        ek[(size_t)(b * S + s) * K + kq + 4 * j] = acc[j];
}

// ---------------------------------------------------------------------------
// Recurrence. ONE block per b (256 blocks -> single occupancy round; R8's
// 512 blocks at 1 block/CU ran two serialized rounds). 256 threads = 4 waves;
// wave w owns cols [64w,64w+64) (4 sub-tiles) x TWO row-groups g (rows 0-15,
// 16-31). Lane (n=lane&15, quad=lane>>4): C/D row = g*16+quad*4+reg, col =
// 64w+16sub+n. U f16 hi/lo B-frags pinned in 256 AGPRs (R8-proven); Uhi/Ulo
// share one 16-deep acc chain per (sub,g) -> acc = 32 VGPR. Total ~195 VGPR
// + 256 AGPR < 512 -> no spill at 1 wave/SIMD.
// Gate dot e_s.h_{s-1} in fp32 VALU at end of prev step (R5-proven). ONE
// barrier/step; h double-buffered f16 LDS plane.
// ---------------------------------------------------------------------------
__global__ __launch_bounds__(256, 1) void recur_kernel(
    const float* __restrict__ enc, const float* __restrict__ eWp,
    const float* __restrict__ keysV, const float* __restrict__ ek,
    const float* __restrict__ U, const int* __restrict__ mask,
    float* __restrict__ out) {
    const int b = blockIdx.x;
    const int t = threadIdx.x;
    const int wave = t >> 6, lane = t & 63;
    const int n = lane & 15, quad = lane >> 4;

    __shared__ u16 hF[2][K][HSTR];       // 2 x 16.3 KB, f16 h planes
    __shared__ float redN[2][K][NW];
    __shared__ float redG[2][K][NW];

    // ---- preload U B-fragments (f16 hi/lo), pin into AGPRs (256) ----
    f16x8 Uhi[NSUB][8], Ulo[NSUB][8];
    #pragma unroll
    for (int sub = 0; sub < NSUB; ++sub) {
        const int col = wave * 64 + sub * 16 + n;
        #pragma unroll
        for (int kt = 0; kt < 8; ++kt) {
            #pragma unroll
            for (int j = 0; j < 8; ++j) {
                const int k = kt * 32 + quad * 8 + j;
                const float u = U[(size_t)k * D + col];
                const _Float16 uh = (_Float16)u;
                Uhi[sub][kt][j] = uh;
                Ulo[sub][kt][j] = (_Float16)(u - (float)uh);
            }
        }
    }
    #pragma unroll
    for (int sub = 0; sub < NSUB; ++sub)
        #pragma unroll
        for (int kt = 0; kt < 8; ++kt)
            asm volatile("" : "+a"(Uhi[sub][kt]), "+a"(Ulo[sub][kt]));

    // ---- per-lane state: 2 row-groups x 4 rows x 4 subs ----
    float upv[2][4][NSUB];
    float rn[2][4];
    float keysVc[2][4][NSUB];
    #pragma unroll
    for (int g = 0; g < 2; ++g)
        #pragma unroll
        for (int reg = 0; reg < 4; ++reg) {
            rn[g][reg] = 1.f;
            const size_t base = (size_t)(b * K + g * 16 + quad * 4 + reg) * D;
            #pragma unroll
            for (int sub = 0; sub < NSUB; ++sub) {
                upv[g][reg][sub] = 0.f;
                keysVc[g][reg][sub] = keysV[base + wave * 64 + sub * 16 + n];
            }
        }

    const int* bm = mask + b * S;
    unsigned long long rem = __ballot(bm[lane & 63] != 0);

    float eWc[NSUB];
    float4 ekv[2];
    #pragma unroll
    for (int sub = 0; sub < NSUB; ++sub) eWc[sub] = 0.f;
    ekv[0] = ekv[1] = make_float4(0.f, 0.f, 0.f, 0.f);
    if (rem) {
        const int s0 = (int)__builtin_ctzll(rem);
        const size_t eo = (size_t)(b * S + s0) * D;
        #pragma unroll
        for (int sub = 0; sub < NSUB; ++sub)
            eWc[sub] = eWp[eo + wave * 64 + sub * 16 + n];
        ekv[0] = *(const float4*)(ek + (size_t)(b * S + s0) * K + quad * 4);
        ekv[1] = *(const float4*)(ek + (size_t)(b * S + s0) * K + 16 + quad * 4);
    }

    int p = 0, q = 0;
    bool first = true;
    while (rem) {
        rem &= rem - 1;
        const int sn = rem ? (int)__builtin_ctzll(rem) : -1;

        // ---- issue ALL next-step loads at loop top (covered by MFMA+VALU) ----
        float e_n[NSUB], eWn[NSUB];
        float4 ekn[2];
        #pragma unroll
        for (int sub = 0; sub < NSUB; ++sub) { e_n[sub] = 0.f; eWn[sub] = 0.f; }
        ekn[0] = ekn[1] = make_float4(0.f, 0.f, 0.f, 0.f);
        if (sn >= 0) {
            const size_t eo = (size_t)(b * S + sn) * D;
            #pragma unroll
            for (int sub = 0; sub < NSUB; ++sub) {
                e_n[sub] = enc[eo + wave * 64 + sub * 16 + n];
                eWn[sub] = eWp[eo + wave * 64 + sub * 16 + n];
            }
            ekn[0] = *(const float4*)(ek + (size_t)(b * S + sn) * K + quad * 4);
            ekn[1] = *(const float4*)(ek + (size_t)(b * S + sn) * K + 16 + quad * 4);
        }

        // ---- MFMA: acc[sub][g] = h_prev[g] @ (Uhi+Ulo), shared 16-deep chains ----
        f32x4 acc[NSUB][2];
        #pragma unroll
        for (int sub = 0; sub < NSUB; ++sub) {
            acc[sub][0] = (f32x4){0.f, 0.f, 0.f, 0.f};
            acc[sub][1] = (f32x4){0.f, 0.f, 0.f, 0.f};
        }
        if (!first) {
            #pragma unroll
            for (int kt = 0; kt < 8; ++kt) {
                const f16x8 a0 = *(const f16x8*)&hF[p][n][kt * 32 + quad * 8];
                const f16x8 a1 = *(const f16x8*)&hF[p][16 + n][kt * 32 + quad * 8];
                #pragma unroll
                for (int sub = 0; sub < NSUB; ++sub) {
                    acc[sub][0] = __builtin_amdgcn_mfma_f32_16x16x32_f16(a0, Uhi[sub][kt], acc[sub][0], 0, 0, 0);
                    acc[sub][0] = __builtin_amdgcn_mfma_f32_16x16x32_f16(a0, Ulo[sub][kt], acc[sub][0], 0, 0, 0);
                    acc[sub][1] = __builtin_amdgcn_mfma_f32_16x16x32_f16(a1, Uhi[sub][kt], acc[sub][1], 0, 0, 0);
                    acc[sub][1] = __builtin_amdgcn_mfma_f32_16x16x32_f16(a1, Ulo[sub][kt], acc[sub][1], 0, 0, 0);
                }
            }
        }

        // ---- gate ----
        float gate[2][4];
        #pragma unroll
        for (int g = 0; g < 2; ++g)
            #pragma unroll
            for (int reg = 0; reg < 4; ++reg) {
                const float4 ekq = ekv[g];
                const float ekb = (reg == 0) ? ekq.x : (reg == 1) ? ekq.y
                                : (reg == 2) ? ekq.z : ekq.w;
                float gg = ekb;
                if (!first) {
                    const float4 g4 = *(const float4*)redG[q ^ 1][g * 16 + quad * 4 + reg];
                    gg += rn[g][reg] * (g4.x + g4.y + g4.z + g4.w);
                }
                gate[g][reg] = 1.f / (1.f + __expf(-gg));
            }

        // ---- update + f16 h write + norm/gate-dot partials ----
        const int pw = p ^ 1;
        float pn[2][4], gd[2][4];
        #pragma unroll
        for (int g = 0; g < 2; ++g)
            #pragma unroll
            for (int reg = 0; reg < 4; ++reg) {
                const int row = g * 16 + quad * 4 + reg;
                float sq = 0.f, dv = 0.f;
                #pragma unroll
                for (int sub = 0; sub < NSUB; ++sub) {
                    float ht = rn[g][reg] * acc[sub][g][reg] + keysVc[g][reg][sub] + eWc[sub];
                    ht = fmaxf(ht, 0.f);
                    const float u2 = rn[g][reg] * upv[g][reg][sub] + gate[g][reg] * ht;
                    upv[g][reg][sub] = u2;
                    sq += u2 * u2;
                    dv += u2 * e_n[sub];
                    hF[pw][row][wave * 64 + sub * 16 + n] = h_bits((_Float16)u2);
                }
                pn[g][reg] = sq;
                gd[g][reg] = dv;
            }

        #pragma unroll
        for (int m = 1; m <= 8; m <<= 1) {
            #pragma unroll
            for (int g = 0; g < 2; ++g)
                #pragma unroll
                for (int reg = 0; reg < 4; ++reg) {
                    pn[g][reg] += __shfl_xor(pn[g][reg], m);
                    gd[g][reg] += __shfl_xor(gd[g][reg], m);
                }
        }
        if (n == 0) {
            #pragma unroll
            for (int g = 0; g < 2; ++g)
                #pragma unroll
                for (int reg = 0; reg < 4; ++reg) {
                    redN[q][g * 16 + quad * 4 + reg][wave] = pn[g][reg];
                    redG[q][g * 16 + quad * 4 + reg][wave] = gd[g][reg];
                }
        }

        __syncthreads();   // the ONLY barrier

        #pragma unroll
        for (int g = 0; g < 2; ++g)
            #pragma unroll
            for (int reg = 0; reg < 4; ++reg) {
                const float4 r4 = *(const float4*)redN[q][g * 16 + quad * 4 + reg];
                rn[g][reg] = rsqrtf(fmaxf(r4.x + r4.y + r4.z + r4.w, 1e-12f));
            }
        #pragma unroll
        for (int sub = 0; sub < NSUB; ++sub) eWc[sub] = eWn[sub];
        ekv[0] = ekn[0]; ekv[1] = ekn[1];
        p ^= 1; q ^= 1; first = false;
    }

    #pragma unroll
    for (int g = 0; g < 2; ++g)
        #pragma unroll
        for (int reg = 0; reg < 4; ++reg) {
            const size_t base = (size_t)(b * K + g * 16 + quad * 4 + reg) * D;
            #pragma unroll
            for (int sub = 0; sub < NSUB; ++sub)
                out[base + wave * 64 + sub * 16 + n] = rn[g][reg] * upv[g][reg][sub];
        }
}

extern "C" void kernel_launch(void* const* d_in, const int* in_sizes, int n_in,
                              void* d_out, int out_size, void* d_ws, size_t ws_size,
                              hipStream_t stream) {
    const int*   prgrph = (const int*)d_in[0];
    const void*  pmask  = d_in[1];
    const float* keys   = (const float*)d_in[2];
    const float* E      = (const float*)d_in[3];
    const float* U      = (const float*)d_in[4];
    const float* V      = (const float*)d_in[5];
    const float* W      = (const float*)d_in[6];
    float* out = (float*)d_out;

    float* ws_enc   = (float*)d_ws;                          // B*S*D  (8 MB)
    float* ws_eW    = ws_enc + (size_t)B * S * D;            // B*S*D  (8 MB)
    float* ws_keysV = ws_eW  + (size_t)B * S * D;            // B*K*D  (4 MB)
    float* ws_ek    = ws_keysV + (size_t)B * K * D;          // B*S*K  (1 MB)
    int*   ws_mask  = (int*)(ws_ek + (size_t)B * S * K);     // B*S

    mask_kernel<<<1, 256, 0, stream>>>(pmask, ws_mask);
    embed_kernel<<<(B * S) / 4, 256, 0, stream>>>(prgrph, E, ws_enc);
    gemm_f32_kernel<<<(B * S) / 32, 256, 0, stream>>>(ws_enc, W, ws_eW);
    gemm_f32_kernel<<<(B * K) / 32, 256, 0, stream>>>(keys, V, ws_keysV);
    ek_kernel<<<B, 256, 0, stream>>>(ws_enc, keys, ws_ek);
    recur_kernel<<<B, 256, 0, stream>>>(
        ws_enc, ws_eW, ws_keysV, ws_ek, U, ws_mask, out);
}

// Round 10
// 308.217 us; speedup vs baseline: 1.2646x; 1.2646x over previous
//
#include <hip/hip_runtime.h>

#define D 256
#define B 128
#define S 64
#define L 32
#define K 32
#define KH 16
#define NW 8      // waves per recurrence block (512 threads), 32 cols/wave
#define NSUB 2    // 16-col sub-tiles per wave
#define HSTR 260  // u16 stride (proven 0-conflict R7/R8)

typedef _Float16 f16x8 __attribute__((ext_vector_type(8)));  // 8 f16 in 4 VGPRs
typedef float f32x4 __attribute__((ext_vector_type(4)));
typedef unsigned short u16;

__device__ __forceinline__ u16 h_bits(_Float16 h) {
    union { _Float16 h; u16 u; } x; x.h = h; return x.u;
}

// ---------------------------------------------------------------------------
// sent_mask extraction, robust to bool shipped as 1-byte or int32.
// ---------------------------------------------------------------------------
__global__ void mask_kernel(const void* mraw, int* mask_out) {
    __shared__ int flag;
    const int tid = threadIdx.x;
    if (tid == 0) flag = 0;
    __syncthreads();
    const unsigned int* w32 = (const unsigned int*)mraw;
    int loc = 0;
    for (int i = tid; i < 1024; i += 256)
        if (w32[i] > 1u) loc = 1;
    if (loc) flag = 1;   // benign race
    __syncthreads();
    const bool is_bytes = (flag != 0);
    const unsigned char* b8 = (const unsigned char*)mraw;
    const int* i32 = (const int*)mraw;
    for (int i = tid; i < B * S; i += 256)
        mask_out[i] = is_bytes ? (int)b8[(size_t)i * L] : i32[(size_t)i * L];
}

// ---------------------------------------------------------------------------
// enc_sents[b,s,:] = sum_l E[prgrph[b,s,l], :]  (2048 blocks, float4 gathers)
// ---------------------------------------------------------------------------
__global__ __launch_bounds__(256) void embed_kernel(
    const int* __restrict__ prgrph, const float* __restrict__ E,
    float* __restrict__ enc) {
    const int t = threadIdx.x;
    const int g = t >> 6;                // sentence within block
    const int bs = blockIdx.x * 4 + g;
    const int c4 = t & 63;               // float4 column group
    __shared__ int sidx[4][L];
    if (t < 4 * L) sidx[t >> 5][t & 31] = prgrph[(size_t)blockIdx.x * 4 * L + t];
    __syncthreads();
    const float4* E4 = (const float4*)E;
    float4 a = make_float4(0.f, 0.f, 0.f, 0.f);
    #pragma unroll
    for (int l = 0; l < L; ++l) {
        const float4 v = E4[(size_t)sidx[g][l] * (D / 4) + c4];
        a.x += v.x; a.y += v.y; a.z += v.z; a.w += v.w;
    }
    *(float4*)&enc[(size_t)bs * D + c4 * 4] = a;
}

// ---------------------------------------------------------------------------
// O[r,:] = A[r,:] @ Bm, 32 rows/block (enc@W and keys@V).
// ---------------------------------------------------------------------------
__global__ __launch_bounds__(256) void gemm_f32_kernel(
    const float* __restrict__ A, const float* __restrict__ Bm,
    float* __restrict__ O) {
    const int row0 = blockIdx.x * 32;
    const int t = threadIdx.x, wave = t >> 6, lane = t & 63;
    __shared__ float a_s[32 * D];
    const float4* Ag = (const float4*)(A + (size_t)row0 * D);
    float4* As4 = (float4*)a_s;
    for (int i = t; i < 32 * D / 4; i += 256) As4[i] = Ag[i];
    __syncthreads();
    const int r0 = wave * 8, c0 = lane * 4;
    float4 acc[8];
    #pragma unroll
    for (int i = 0; i < 8; ++i) acc[i] = make_float4(0.f, 0.f, 0.f, 0.f);
    for (int d = 0; d < D; d += 4) {
        float4 av[8];
        #pragma unroll
        for (int i = 0; i < 8; ++i) av[i] = *(const float4*)&a_s[(r0 + i) * D + d];
        #pragma unroll
        for (int j = 0; j < 4; ++j) {
            const float4 w = *(const float4*)(Bm + (size_t)(d + j) * D + c0);
            #pragma unroll
            for (int i = 0; i < 8; ++i) {
                const float a = (j == 0) ? av[i].x : (j == 1) ? av[i].y
                              : (j == 2) ? av[i].z : av[i].w;
                acc[i].x += a * w.x; acc[i].y += a * w.y;
                acc[i].z += a * w.z; acc[i].w += a * w.w;
            }
        }
    }
    #pragma unroll
    for (int i = 0; i < 8; ++i)
        *(float4*)&O[(size_t)(row0 + r0 + i) * D + c0] = acc[i];
}

// ---------------------------------------------------------------------------
// ek[b,s,k] = enc[b,s,:] . keys[b,k,:]
// ---------------------------------------------------------------------------
__global__ __launch_bounds__(256) void ek_kernel(
    const float* __restrict__ enc, const float* __restrict__ keys,
    float* __restrict__ ek) {
    const int b = blockIdx.x, t = threadIdx.x;
    __shared__ float ks[K][D + 4];
    const float4* kg = (const float4*)(keys + (size_t)b * K * D);
    for (int i = t; i < K * D / 4; i += 256)
        *(float4*)&ks[i >> 6][(i & 63) * 4] = kg[i];
    __syncthreads();
    const int s = t >> 2, kq = t & 3;          // k = kq + 4j
    const float4* e4 = (const float4*)(enc + (size_t)(b * S + s) * D);
    float acc[8];
    #pragma unroll
    for (int j = 0; j < 8; ++j) acc[j] = 0.f;
    for (int d4 = 0; d4 < D / 4; ++d4) {
        const float4 e = e4[d4];
        #pragma unroll
        for (int j = 0; j < 8; ++j) {
            const float4 kv = *(const float4*)&ks[kq + 4 * j][d4 * 4];
            acc[j] += e.x * kv.x + e.y * kv.y + e.z * kv.z + e.w * kv.w;
        }
    }
    #pragma unroll
    for (int j = 0; j < 8; ++j)
        ek[(size_t)(b * S + s) * K + kq + 4 * j] = acc[j];
}

// ---------------------------------------------------------------------------
// Recurrence. Block = (b, 16-row half of K); 512 threads = 8 waves; wave w
// owns cols [32w,32w+32) = 2 sub-tiles. Lane (n=lane&15, quad=lane>>4):
// C/D row = quad*4+reg, col = 32w+16sub+n.
// KEY (R9 post-mortem): co-residency beats fewer rounds. U f16 hi/lo frags =
// 128 AGPRs/wave (asm "+a" pin, R8-proven); remaining VGPR demand ~110 fits
// the 256 unified budget of __launch_bounds__(512,2) -> 2 blocks/CU, all 512
// blocks in ONE occupancy round, 16 waves/CU: one block's barrier drain is
// covered by the other block's MFMAs.
// Gate dot e_s.h_{s-1} in fp32 VALU at end of prev step (R5-proven). ONE
// barrier/step; h double-buffered f16 LDS plane (R8-proven).
// ek is indexed by ABSOLUTE entity -> kh offset required (R3 bug).
// ---------------------------------------------------------------------------
__global__ __launch_bounds__(512, 2) void recur_kernel(
    const float* __restrict__ enc, const float* __restrict__ eWp,
    const float* __restrict__ keysV, const float* __restrict__ ek,
    const float* __restrict__ U, const int* __restrict__ mask,
    float* __restrict__ out) {
    const int b  = blockIdx.x >> 1;
    const int kh = (blockIdx.x & 1) * KH;
    const int t = threadIdx.x;
    const int wave = t >> 6, lane = t & 63;
    const int n = lane & 15, quad = lane >> 4;

    __shared__ u16 hF[2][KH][HSTR];      // 2 x 8.1 KB, f16 h planes
    __shared__ float redN[2][KH][NW];
    __shared__ float redG[2][KH][NW];

    // ---- preload U B-fragments (f16 hi/lo): 2 subs x 8 kt -> 128 AGPRs ----
    f16x8 Uhi[NSUB][8], Ulo[NSUB][8];
    #pragma unroll
    for (int sub = 0; sub < NSUB; ++sub) {
        const int col = wave * 32 + sub * 16 + n;
        #pragma unroll
        for (int kt = 0; kt < 8; ++kt) {
            #pragma unroll
            for (int j = 0; j < 8; ++j) {
                const int k = kt * 32 + quad * 8 + j;
                const float u = U[(size_t)k * D + col];
                const _Float16 uh = (_Float16)u;
                Uhi[sub][kt][j] = uh;
                Ulo[sub][kt][j] = (_Float16)(u - (float)uh);
            }
        }
    }
    #pragma unroll
    for (int sub = 0; sub < NSUB; ++sub)
        #pragma unroll
        for (int kt = 0; kt < 8; ++kt)
            asm volatile("" : "+a"(Uhi[sub][kt]), "+a"(Ulo[sub][kt]));

    // ---- per-lane state ----
    float upv[4][NSUB];
    float rn[4];
    float keysVc[4][NSUB];
    #pragma unroll
    for (int reg = 0; reg < 4; ++reg) {
        rn[reg] = 1.f;
        const size_t base = (size_t)(b * K + kh + quad * 4 + reg) * D;
        #pragma unroll
        for (int sub = 0; sub < NSUB; ++sub) {
            upv[reg][sub] = 0.f;
            keysVc[reg][sub] = keysV[base + wave * 32 + sub * 16 + n];
        }
    }

    const int* bm = mask + b * S;
    unsigned long long rem = __ballot(bm[lane & 63] != 0);

    float eWc[NSUB];
    float4 ekv = make_float4(0.f, 0.f, 0.f, 0.f);
    #pragma unroll
    for (int sub = 0; sub < NSUB; ++sub) eWc[sub] = 0.f;
    if (rem) {
        const int s0 = (int)__builtin_ctzll(rem);
        const size_t eo = (size_t)(b * S + s0) * D;
        #pragma unroll
        for (int sub = 0; sub < NSUB; ++sub)
            eWc[sub] = eWp[eo + wave * 32 + sub * 16 + n];
        ekv = *(const float4*)(ek + (size_t)(b * S + s0) * K + kh + quad * 4);
    }

    int p = 0, q = 0;
    bool first = true;
    while (rem) {
        rem &= rem - 1;
        const int sn = rem ? (int)__builtin_ctzll(rem) : -1;

        // ---- issue next-step e load early (covered by MFMA) ----
        float e_n[NSUB];
        #pragma unroll
        for (int sub = 0; sub < NSUB; ++sub) e_n[sub] = 0.f;
        if (sn >= 0) {
            const size_t eo = (size_t)(b * S + sn) * D;
            #pragma unroll
            for (int sub = 0; sub < NSUB; ++sub)
                e_n[sub] = enc[eo + wave * 32 + sub * 16 + n];
        }

        // ---- MFMA: acc = h_prev @ (Uhi,Ulo), 4 indep chains of 8 ----
        f32x4 acc[NSUB][2];
        #pragma unroll
        for (int sub = 0; sub < NSUB; ++sub) {
            acc[sub][0] = (f32x4){0.f, 0.f, 0.f, 0.f};
            acc[sub][1] = (f32x4){0.f, 0.f, 0.f, 0.f};
        }
        if (!first) {
            #pragma unroll
            for (int kt = 0; kt < 8; ++kt) {
                const f16x8 av = *(const f16x8*)&hF[p][n][kt * 32 + quad * 8];
                #pragma unroll
                for (int sub = 0; sub < NSUB; ++sub) {
                    acc[sub][0] = __builtin_amdgcn_mfma_f32_16x16x32_f16(av, Uhi[sub][kt], acc[sub][0], 0, 0, 0);
                    acc[sub][1] = __builtin_amdgcn_mfma_f32_16x16x32_f16(av, Ulo[sub][kt], acc[sub][1], 0, 0, 0);
                }
            }
        }

        // ---- gate ----
        float gate[4];
        #pragma unroll
        for (int reg = 0; reg < 4; ++reg) {
            const float ekb = (reg == 0) ? ekv.x : (reg == 1) ? ekv.y
                            : (reg == 2) ? ekv.z : ekv.w;
            float g = ekb;
            if (!first) {
                const float* rg = redG[q ^ 1][quad * 4 + reg];
                const float4 g0 = *(const float4*)rg;
                const float4 g1 = *(const float4*)(rg + 4);
                g += rn[reg] * (g0.x + g0.y + g0.z + g0.w +
                                g1.x + g1.y + g1.z + g1.w);
            }
            gate[reg] = 1.f / (1.f + __expf(-g));
        }

        // ---- update + f16 h write + norm/gate-dot partials ----
        const int pw = p ^ 1;
        float pn[4], gd[4];
        #pragma unroll
        for (int reg = 0; reg < 4; ++reg) {
            const int row = quad * 4 + reg;
            float sq = 0.f, dv = 0.f;
            #pragma unroll
            for (int sub = 0; sub < NSUB; ++sub) {
                const float asum = acc[sub][0][reg] + acc[sub][1][reg];
                float ht = rn[reg] * asum + keysVc[reg][sub] + eWc[sub];
                ht = fmaxf(ht, 0.f);
                const float u2 = rn[reg] * upv[reg][sub] + gate[reg] * ht;
                upv[reg][sub] = u2;
                sq += u2 * u2;
                dv += u2 * e_n[sub];
                hF[pw][row][wave * 32 + sub * 16 + n] = h_bits((_Float16)u2);
            }
            pn[reg] = sq;
            gd[reg] = dv;
        }

        // ---- reload step-invariants IN PLACE (last use passed) ----
        if (sn >= 0) {
            const size_t eo = (size_t)(b * S + sn) * D;
            #pragma unroll
            for (int sub = 0; sub < NSUB; ++sub)
                eWc[sub] = eWp[eo + wave * 32 + sub * 16 + n];
            ekv = *(const float4*)(ek + (size_t)(b * S + sn) * K + kh + quad * 4);
        }

        #pragma unroll
        for (int m = 1; m <= 8; m <<= 1) {
            #pragma unroll
            for (int reg = 0; reg < 4; ++reg) {
                pn[reg] += __shfl_xor(pn[reg], m);
                gd[reg] += __shfl_xor(gd[reg], m);
            }
        }
        if (n == 0) {
            #pragma unroll
            for (int reg = 0; reg < 4; ++reg) {
                redN[q][quad * 4 + reg][wave] = pn[reg];
                redG[q][quad * 4 + reg][wave] = gd[reg];
            }
        }

        __syncthreads();   // the ONLY barrier

        #pragma unroll
        for (int reg = 0; reg < 4; ++reg) {
            const float* rp = redN[q][quad * 4 + reg];
            const float4 r0 = *(const float4*)rp;
            const float4 r1 = *(const float4*)(rp + 4);
            rn[reg] = rsqrtf(fmaxf(r0.x + r0.y + r0.z + r0.w +
                                   r1.x + r1.y + r1.z + r1.w, 1e-12f));
        }
        p ^= 1; q ^= 1; first = false;
    }

    #pragma unroll
    for (int reg = 0; reg < 4; ++reg) {
        const size_t base = (size_t)(b * K + kh + quad * 4 + reg) * D;
        #pragma unroll
        for (int sub = 0; sub < NSUB; ++sub)
            out[base + wave * 32 + sub * 16 + n] = rn[reg] * upv[reg][sub];
    }
}

extern "C" void kernel_launch(void* const* d_in, const int* in_sizes, int n_in,
                              void* d_out, int out_size, void* d_ws, size_t ws_size,
                              hipStream_t stream) {
    const int*   prgrph = (const int*)d_in[0];
    const void*  pmask  = d_in[1];
    const float* keys   = (const float*)d_in[2];
    const float* E      = (const float*)d_in[3];
    const float* U      = (const float*)d_in[4];
    const float* V      = (const float*)d_in[5];
    const float* W      = (const float*)d_in[6];
    float* out = (float*)d_out;

    float* ws_enc   = (float*)d_ws;                          // B*S*D  (8 MB)
    float* ws_eW    = ws_enc + (size_t)B * S * D;            // B*S*D  (8 MB)
    float* ws_keysV = ws_eW  + (size_t)B * S * D;            // B*K*D  (4 MB)
    float* ws_ek    = ws_keysV + (size_t)B * K * D;          // B*S*K  (1 MB)
    int*   ws_mask  = (int*)(ws_ek + (size_t)B * S * K);     // B*S

    mask_kernel<<<1, 256, 0, stream>>>(pmask, ws_mask);
    embed_kernel<<<(B * S) / 4, 256, 0, stream>>>(prgrph, E, ws_enc);
    gemm_f32_kernel<<<(B * S) / 32, 256, 0, stream>>>(ws_enc, W, ws_eW);
    gemm_f32_kernel<<<(B * K) / 32, 256, 0, stream>>>(keys, V, ws_keysV);
    ek_kernel<<<B, 256, 0, stream>>>(ws_enc, keys, ws_ek);
    recur_kernel<<<B * (K / KH), 512, 0, stream>>>(
        ws_enc, ws_eW, ws_keysV, ws_ek, U, ws_mask, out);
}